// Round 8
// baseline (268.493 us; speedup 1.0000x reference)
//
#include <hip/hip_runtime.h>

#define W 320
#define H 96
#define FS 96
#define BS 8
#define NPLANES 9
#define CPW 12            // channels per wave (FS / 8 waves)
#define NTHREADS 512      // 8 waves per block, one (b,y) row per block
#define RSTRIDE 49        // odd stride -> conflict-free lane slots (45 used)

// 4-byte-aligned float4: x0 = 5*lane is only dword-aligned
typedef float f4 __attribute__((ext_vector_type(4), aligned(4)));

__global__ __launch_bounds__(NTHREADS, 6)   // 6 waves/EU = 3 blocks/CU -> VGPR <= ~85
void cost_volume_kernel(const float* __restrict__ f1,
                        const float* __restrict__ f2,
                        float* __restrict__ out)
{
    // 4 reduction slots x 64 lanes x 49 floats = 50,176 B -> 3 blocks/CU
    __shared__ float red[4 * 64 * RSTRIDE];

    const int t   = threadIdx.x;
    const int wv  = t >> 6;          // wave 0..7
    const int l   = t & 63;          // lane
    const int row = blockIdx.x;      // 0..767 = (b, y)
    const int b   = row / H;
    const int y   = row % H;

    // lane covers output cols x0..x0+4 (VX=5; 64*5 = 320 exactly)
    const int x0 = 5 * l;
    // f2 window: cols x0-4 .. x0+12, as 3 quads + 1 scalar with edge-clamped
    // addresses; clamped lanes' values zeroed by bitmask (AND, not mul:
    // clamped reads may be Inf/NaN).
    const int o0 = (x0 - 4 < 0)   ? 0   : x0 - 4;   // quad: e0..e3
    const int o2 = (x0 + 4 > 316) ? 316 : x0 + 4;   // quad: e8..e11
    const int o3 = (x0 + 8 > 319) ? 319 : x0 + 8;   // scalar: e12
    const unsigned mlo = (l == 0)  ? 0u : ~0u;
    const unsigned mhi = (l == 63) ? 0u : ~0u;
    const bool hi = (l == 63);                      // e8 (col 319) = q2.w

    const size_t rowoff = ((size_t)(b * FS) * H + y) * W;
    const float* f1w = f1 + rowoff + (size_t)(wv * CPW) * (H * W);
    const float* f2w = f2 + rowoff + (size_t)(wv * CPW) * (H * W);

    float acc[5][9];
#pragma unroll
    for (int j = 0; j < 5; ++j)
#pragma unroll
        for (int p = 0; p < 9; ++p) acc[j][p] = 0.f;

    // ---- streaming channel loop: no LDS, no barriers, pure load->FMA ----
#pragma unroll 4
    for (int cc = 0; cc < CPW; ++cc) {
        const float* f1c = f1w + (size_t)cc * (H * W);
        const float* f2c = f2w + (size_t)cc * (H * W);

        const f4   q0 = *(const f4*)(f2c + o0);
        const f4   q1 = *(const f4*)(f2c + x0);      // e4..e7, always valid
        const f4   q2 = *(const f4*)(f2c + o2);
        const float s3 = f2c[o3];
        const f4   af = *(const f4*)(f1c + x0);      // a0..a3, always valid
        const float a4 = f1c[x0 + 4];                // x0+4 <= 319

        float w_[13];
        w_[0]  = __uint_as_float(__float_as_uint(q0.x) & mlo);
        w_[1]  = __uint_as_float(__float_as_uint(q0.y) & mlo);
        w_[2]  = __uint_as_float(__float_as_uint(q0.z) & mlo);
        w_[3]  = __uint_as_float(__float_as_uint(q0.w) & mlo);
        w_[4]  = q1.x;  w_[5] = q1.y;  w_[6] = q1.z;  w_[7] = q1.w;
        w_[8]  = hi ? q2.w : q2.x;   // lane63's q2 clamped to 316 -> col319=.w
        w_[9]  = __uint_as_float(__float_as_uint(q2.y) & mhi);
        w_[10] = __uint_as_float(__float_as_uint(q2.z) & mhi);
        w_[11] = __uint_as_float(__float_as_uint(q2.w) & mhi);
        w_[12] = __uint_as_float(__float_as_uint(s3)   & mhi);

        const float a_[5] = { af.x, af.y, af.z, af.w, a4 };

        // plane p <-> shift i = p-4; window index e = j + 8 - p
#pragma unroll
        for (int j = 0; j < 5; ++j)
#pragma unroll
            for (int p = 0; p < 9; ++p)
                acc[j][p] = fmaf(a_[j], w_[j + 8 - p], acc[j][p]);
    }

    // ---- 3-phase LDS tree reduction: 8 waves -> wave 0 ----
#define PARK(slot_) do {                                                     \
    float* dst_ = &red[((slot_) * 64 + l) * RSTRIDE];                        \
    _Pragma("unroll")                                                        \
    for (int j = 0; j < 5; ++j)                                              \
        _Pragma("unroll")                                                    \
        for (int p = 0; p < 9; ++p) dst_[j * 9 + p] = acc[j][p];             \
} while (0)

#define GRAB(slot_) do {                                                     \
    const float* src_ = &red[((slot_) * 64 + l) * RSTRIDE];                  \
    _Pragma("unroll")                                                        \
    for (int j = 0; j < 5; ++j)                                              \
        _Pragma("unroll")                                                    \
        for (int p = 0; p < 9; ++p) acc[j][p] += src_[j * 9 + p];            \
} while (0)

    if (wv >= 4) PARK(wv - 4);
    __syncthreads();
    if (wv < 4) GRAB(wv);
    __syncthreads();                 // anti-dep: reads done before re-write
    if (wv == 2 || wv == 3) PARK(wv);
    __syncthreads();
    if (wv < 2) GRAB(wv + 2);
    __syncthreads();
    if (wv == 1) PARK(0);
    __syncthreads();
    if (wv == 0) {
        GRAB(0);
        const float scale = 1.0f / (float)FS;
#pragma unroll
        for (int p = 0; p < 9; ++p) {
            float* op = out + (((size_t)(b * NPLANES + p)) * H + y) * W + x0;
            f4 v;
            v.x = acc[0][p] * scale;
            v.y = acc[1][p] * scale;
            v.z = acc[2][p] * scale;
            v.w = acc[3][p] * scale;
            *(f4*)op = v;
            op[4] = acc[4][p] * scale;
        }
    }

#undef PARK
#undef GRAB
}

extern "C" void kernel_launch(void* const* d_in, const int* in_sizes, int n_in,
                              void* d_out, int out_size, void* d_ws, size_t ws_size,
                              hipStream_t stream) {
    (void)in_sizes; (void)n_in; (void)d_ws; (void)ws_size; (void)out_size;
    const float* f1 = (const float*)d_in[0];
    const float* f2 = (const float*)d_in[1];
    float* out = (float*)d_out;

    dim3 grid(BS * H);        // 768 blocks x 8 waves = 24 waves/CU
    dim3 block(NTHREADS);
    cost_volume_kernel<<<grid, block, 0, stream>>>(f1, f2, out);
}

// Round 10
// 209.927 us; speedup vs baseline: 1.2790x; 1.2790x over previous
//
#include <hip/hip_runtime.h>

#define W 320
#define H 96
#define FS 96
#define BS 8
#define NPLANES 9
#define CPW 12            // channels per wave (FS / 8 waves)
#define NTHREADS 512      // 8 waves per block, one (b,y) row per block
#define RSTRIDE 45        // contiguous 45-float lane slots; odd stride -> 2-way
                          // bank aliasing only (free per m136)

// 4-byte-aligned float4: x0 = 5*lane is only dword-aligned
typedef float f4 __attribute__((ext_vector_type(4), aligned(4)));

// NO min-waves clamp. Round-8 post-mortem: __launch_bounds__(512,6) made the
// allocator squeeze to 40 VGPR and spill acc[45] to scratch (WRITE_SIZE
// 8.6->216 MB, 137us). This loop wants ~72 VGPR (round-7 measured), which
// already fits 6 waves/SIMD (512/6=85) without any forced cap.
__global__ __launch_bounds__(NTHREADS)
void cost_volume_kernel(const float* __restrict__ f1,
                        const float* __restrict__ f2,
                        float* __restrict__ out)
{
    // 4 reduction slots x 64 lanes x 45 floats = 46,080 B
    // -> 3 blocks/CU (138 KB <= 160 KB) = 24 waves/CU
    __shared__ float red[4 * 64 * RSTRIDE];

    const int t   = threadIdx.x;
    const int wv  = t >> 6;          // wave 0..7
    const int l   = t & 63;          // lane
    const int row = blockIdx.x;      // 0..767 = (b, y)
    const int b   = row / H;
    const int y   = row % H;

    // lane covers output cols x0..x0+4 (VX=5; 64*5 = 320 exactly)
    const int x0 = 5 * l;
    // f2 window: cols x0-4 .. x0+12, as 3 quads + 1 scalar with edge-clamped
    // addresses; clamped lanes' values zeroed by bitmask (AND, not mul:
    // clamped reads may be Inf/NaN).
    const int o0 = (x0 - 4 < 0)   ? 0   : x0 - 4;   // quad: e0..e3
    const int o2 = (x0 + 4 > 316) ? 316 : x0 + 4;   // quad: e8..e11
    const int o3 = (x0 + 8 > 319) ? 319 : x0 + 8;   // scalar: e12
    const unsigned mlo = (l == 0)  ? 0u : ~0u;
    const unsigned mhi = (l == 63) ? 0u : ~0u;
    const bool hi = (l == 63);                      // e8 (col 319) = q2.w

    const size_t rowoff = ((size_t)(b * FS) * H + y) * W;
    const float* f1w = f1 + rowoff + (size_t)(wv * CPW) * (H * W);
    const float* f2w = f2 + rowoff + (size_t)(wv * CPW) * (H * W);

    float acc[5][9];
#pragma unroll
    for (int j = 0; j < 5; ++j)
#pragma unroll
        for (int p = 0; p < 9; ++p) acc[j][p] = 0.f;

    // ---- streaming channel loop: no LDS, no barriers, pure load->FMA ----
#pragma unroll 4
    for (int cc = 0; cc < CPW; ++cc) {
        const float* f1c = f1w + (size_t)cc * (H * W);
        const float* f2c = f2w + (size_t)cc * (H * W);

        const f4   q0 = *(const f4*)(f2c + o0);
        const f4   q1 = *(const f4*)(f2c + x0);      // e4..e7, always valid
        const f4   q2 = *(const f4*)(f2c + o2);
        const float s3 = f2c[o3];
        const f4   af = *(const f4*)(f1c + x0);      // a0..a3, always valid
        const float a4 = f1c[x0 + 4];                // x0+4 <= 319

        float w_[13];
        w_[0]  = __uint_as_float(__float_as_uint(q0.x) & mlo);
        w_[1]  = __uint_as_float(__float_as_uint(q0.y) & mlo);
        w_[2]  = __uint_as_float(__float_as_uint(q0.z) & mlo);
        w_[3]  = __uint_as_float(__float_as_uint(q0.w) & mlo);
        w_[4]  = q1.x;  w_[5] = q1.y;  w_[6] = q1.z;  w_[7] = q1.w;
        w_[8]  = hi ? q2.w : q2.x;   // lane63's q2 clamped to 316 -> col319=.w
        w_[9]  = __uint_as_float(__float_as_uint(q2.y) & mhi);
        w_[10] = __uint_as_float(__float_as_uint(q2.z) & mhi);
        w_[11] = __uint_as_float(__float_as_uint(q2.w) & mhi);
        w_[12] = __uint_as_float(__float_as_uint(s3)   & mhi);

        const float a_[5] = { af.x, af.y, af.z, af.w, a4 };

        // plane p <-> shift i = p-4; window index e = j + 8 - p
#pragma unroll
        for (int j = 0; j < 5; ++j)
#pragma unroll
            for (int p = 0; p < 9; ++p)
                acc[j][p] = fmaf(a_[j], w_[j + 8 - p], acc[j][p]);
    }

    // ---- 3-phase LDS tree reduction: 8 waves -> wave 0 ----
#define PARK(slot_) do {                                                     \
    float* dst_ = &red[((slot_) * 64 + l) * RSTRIDE];                        \
    _Pragma("unroll")                                                        \
    for (int j = 0; j < 5; ++j)                                              \
        _Pragma("unroll")                                                    \
        for (int p = 0; p < 9; ++p) dst_[j * 9 + p] = acc[j][p];             \
} while (0)

#define GRAB(slot_) do {                                                     \
    const float* src_ = &red[((slot_) * 64 + l) * RSTRIDE];                  \
    _Pragma("unroll")                                                        \
    for (int j = 0; j < 5; ++j)                                              \
        _Pragma("unroll")                                                    \
        for (int p = 0; p < 9; ++p) acc[j][p] += src_[j * 9 + p];            \
} while (0)

    if (wv >= 4) PARK(wv - 4);
    __syncthreads();
    if (wv < 4) GRAB(wv);
    __syncthreads();                 // anti-dep: reads done before re-write
    if (wv == 2 || wv == 3) PARK(wv);
    __syncthreads();
    if (wv < 2) GRAB(wv + 2);
    __syncthreads();
    if (wv == 1) PARK(0);
    __syncthreads();
    if (wv == 0) {
        GRAB(0);
        const float scale = 1.0f / (float)FS;
#pragma unroll
        for (int p = 0; p < 9; ++p) {
            float* op = out + (((size_t)(b * NPLANES + p)) * H + y) * W + x0;
            f4 v;
            v.x = acc[0][p] * scale;
            v.y = acc[1][p] * scale;
            v.z = acc[2][p] * scale;
            v.w = acc[3][p] * scale;
            *(f4*)op = v;
            op[4] = acc[4][p] * scale;
        }
    }

#undef PARK
#undef GRAB
}

extern "C" void kernel_launch(void* const* d_in, const int* in_sizes, int n_in,
                              void* d_out, int out_size, void* d_ws, size_t ws_size,
                              hipStream_t stream) {
    (void)in_sizes; (void)n_in; (void)d_ws; (void)ws_size; (void)out_size;
    const float* f1 = (const float*)d_in[0];
    const float* f2 = (const float*)d_in[1];
    float* out = (float*)d_out;

    dim3 grid(BS * H);        // 768 blocks x 8 waves = 24 waves/CU target
    dim3 block(NTHREADS);
    cost_volume_kernel<<<grid, block, 0, stream>>>(f1, f2, out);
}